// Round 1
// baseline (1654.506 us; speedup 1.0000x reference)
//
#include <hip/hip_runtime.h>

#define NE 32      // experts
#define NK 4       // top-k
#define HD 2048    // hidden
#define ID 1024    // intermediate
#define NT 4096    // tokens
#define TKR (NT*NK) // total routed rows = 16384
#define BM 128
#define BK 64
#define LDA 72     // legacy padded LDS row stride
#define MAXTILES 160

typedef __attribute__((ext_vector_type(8))) short short8;
typedef __attribute__((ext_vector_type(4))) float floatx4;

__device__ __forceinline__ unsigned short f2bf(float f) {
  // round-to-nearest-even fp32 -> bf16
  unsigned u = __builtin_bit_cast(unsigned, f);
  unsigned r = u + 0x7fffu + ((u >> 16) & 1u);
  return (unsigned short)(r >> 16);
}

// async global->LDS, 16B per lane; LDS dest = wave-uniform base + lane*16
#define GLOAD16(g, l) __builtin_amdgcn_global_load_lds( \
    (const __attribute__((address_space(1))) void*)(g), \
    (__attribute__((address_space(3))) void*)(l), 16, 0, 0)

// ---------------- generic fp32 -> bf16 convert (grid-stride) ----------------
__global__ __launch_bounds__(256) void cvt_kernel(const float* __restrict__ src,
                                                  unsigned short* __restrict__ dst,
                                                  size_t n) {
  size_t stride = (size_t)gridDim.x * 256 * 8;
  for (size_t i = ((size_t)blockIdx.x * 256 + threadIdx.x) * 8; i < n; i += stride) {
    float4 a = *(const float4*)(src + i);
    float4 b = *(const float4*)(src + i + 4);
    union { unsigned short s[8]; int4 v; } p;
    p.s[0]=f2bf(a.x); p.s[1]=f2bf(a.y); p.s[2]=f2bf(a.z); p.s[3]=f2bf(a.w);
    p.s[4]=f2bf(b.x); p.s[5]=f2bf(b.y); p.s[6]=f2bf(b.z); p.s[7]=f2bf(b.w);
    *(int4*)(dst + i) = p.v;
  }
}

// ---------------- router: logits -> sigmoid -> top4 -> weights ----------------
__global__ __launch_bounds__(256) void router_kernel(
    const float* __restrict__ x, const float* __restrict__ gate_w,
    const float* __restrict__ bias, int* __restrict__ topk_idx,
    float* __restrict__ topk_w, int* __restrict__ counts) {
  int t = blockIdx.x;
  int tid = threadIdx.x;
  int e = tid >> 3, l8 = tid & 7;     // 8 threads per expert
  const float* xr = x + (size_t)t * HD;
  const float* gr = gate_w + (size_t)e * HD;
  float s = 0.f;
  int base = l8 * 256;
#pragma unroll 8
  for (int i = 0; i < 256; i += 4) {
    float4 xv = *(const float4*)(xr + base + i);
    float4 gv = *(const float4*)(gr + base + i);
    s += xv.x*gv.x + xv.y*gv.y + xv.z*gv.z + xv.w*gv.w;
  }
  s += __shfl_down(s, 4, 64);
  s += __shfl_down(s, 2, 64);
  s += __shfl_down(s, 1, 64);
  __shared__ float sc[NE];
  if (l8 == 0) sc[e] = s;
  __syncthreads();
  if (tid == 0) {
    float sig[NE], sel[NE];
    for (int i = 0; i < NE; i++) {
      sig[i] = 1.f / (1.f + expf(-sc[i]));
      sel[i] = sig[i] + bias[i];       // bias affects selection only
    }
    int idxs[NK]; float wsum = 0.f;
    for (int k = 0; k < NK; k++) {
      int bi = 0; float bv = -1e30f;
      for (int i = 0; i < NE; i++)
        if (sel[i] > bv) { bv = sel[i]; bi = i; }   // ties -> lowest index
      sel[bi] = -1e30f;
      idxs[k] = bi; wsum += sig[bi];
    }
    for (int k = 0; k < NK; k++) {
      topk_idx[t*NK + k] = idxs[k];
      topk_w[t*NK + k] = sig[idxs[k]] / wsum;
      atomicAdd(&counts[idxs[k]], 1);
    }
  }
}

// ---------------- plan: offsets + tile descriptors ----------------
__global__ void plan_kernel(const int* __restrict__ counts, int* __restrict__ offsets,
                            int* __restrict__ cursor, int* __restrict__ tiles,
                            int* __restrict__ numtiles) {
  if (threadIdx.x == 0) {
    int off = 0;
    for (int e = 0; e < NE; e++) { offsets[e] = off; off += counts[e]; cursor[e] = 0; }
    offsets[NE] = off;
    int nt = 0;
    for (int e = 0; e < NE; e++) {
      int start = offsets[e], n = counts[e];
      for (int r = 0; r < n; r += BM) {
        tiles[nt*3+0] = e; tiles[nt*3+1] = start + r; tiles[nt*3+2] = min(BM, n - r);
        nt++;
      }
    }
    *numtiles = nt;
  }
}

// ---------------- scatter to expert-sorted order ----------------
__global__ __launch_bounds__(256) void scatter_kernel(
    const int* __restrict__ topk_idx, const float* __restrict__ topk_w,
    const int* __restrict__ offsets, int* __restrict__ cursor,
    int* __restrict__ sorted_token, float* __restrict__ sorted_w) {
  int i = blockIdx.x * 256 + threadIdx.x;   // [0, TKR)
  int e = topk_idx[i];
  int pos = offsets[e] + atomicAdd(&cursor[e], 1);
  sorted_token[pos] = i >> 2;
  sorted_w[pos] = topk_w[i];
}

// ============================================================================
// NEW PATH: bf16 weights + global_load_lds staging (m97 structure)
//
// LDS layout: linear [128 rows][64 cols] bf16 = 128 B/row = 8 chunks of 16 B.
// Swizzle (rule 21, both-sides): LDS chunk (r, cc) holds GLOBAL chunk
// (cc ^ (r&7)); read of global chunk kc for row r goes to LDS chunk
// kc ^ (r&7).  XOR is an involution, so stage-source swizzle == read swizzle.
// ds_read_b128 bank-group = (kc^(r&7))&7 -> uniform over 8 groups, 2-way only.
// ============================================================================

// ---- GEMM1: gu = X_e @ wb13_e^T, fused SwiGLU*weight -> h bf16 ----
__global__ __launch_bounds__(256) void gemm1_kernel(
    const unsigned short* __restrict__ xb, const unsigned short* __restrict__ wb13,
    const int* __restrict__ tiles, const int* __restrict__ numtiles,
    const int* __restrict__ sorted_token, const float* __restrict__ sorted_w,
    unsigned short* __restrict__ hbuf) {
  int mt = blockIdx.y;
  if (mt >= *numtiles) return;
  int e = tiles[mt*3+0], g0 = tiles[mt*3+1], mrows = tiles[mt*3+2];
  int nb = blockIdx.x * 64;   // gate-col base; up cols at +ID

  __shared__ unsigned short As[BM*BK];
  __shared__ unsigned short Bs[BM*BK];

  int tid = threadIdx.x;
  int wave = tid >> 6, lane = tid & 63;
  int m15 = lane & 15, q = lane >> 4;
  const unsigned short* wbe = wb13 + (size_t)e * (2*ID) * HD;

  // staging descriptors: call i covers chunk c = i*256 + tid
  const unsigned short* asrc[4]; const unsigned short* bsrc[4];
  unsigned short* adst[4]; unsigned short* bdst[4];
#pragma unroll
  for (int i = 0; i < 4; i++) {
    int c = i*256 + tid;
    int r = c >> 3, cc = c & 7;
    int sc = ((cc ^ (r & 7)) << 3);              // swizzled source col (elems)
    int rr = r < mrows ? r : 0;                  // tail clamp (masked at epilogue)
    asrc[i] = xb + (size_t)sorted_token[g0+rr] * HD + sc;
    int sr = (r < 64) ? (nb + r) : (ID + nb + r - 64);  // gate rows | up rows
    bsrc[i] = wbe + (size_t)sr * HD + sc;
    int dchunk = (i*256 + wave*64) * 8;          // wave-uniform LDS elem offset
    adst[i] = &As[dchunk];
    bdst[i] = &Bs[dchunk];
  }

  floatx4 acc[2][8];
  floatx4 zf = {0.f,0.f,0.f,0.f};
#pragma unroll
  for (int mi=0;mi<2;mi++)
#pragma unroll
    for (int ni=0;ni<8;ni++) acc[mi][ni] = zf;

  for (int k0 = 0; k0 < HD; k0 += BK) {
#pragma unroll
    for (int i = 0; i < 4; i++) GLOAD16(asrc[i] + k0, adst[i]);
#pragma unroll
    for (int i = 0; i < 4; i++) GLOAD16(bsrc[i] + k0, bdst[i]);
    __syncthreads();   // compiler emits vmcnt(0) drain before s_barrier
#pragma unroll
    for (int ks = 0; ks < 2; ks++) {
      short8 af[2], bfr[8];
#pragma unroll
      for (int mi = 0; mi < 2; mi++) {
        int row = wave*32 + 16*mi + m15;
        af[mi] = *(const short8*)(&As[row*64 + (((ks*4 + q) ^ (row & 7)) << 3)]);
      }
#pragma unroll
      for (int ni = 0; ni < 8; ni++) {
        int row = 16*ni + m15;
        bfr[ni] = *(const short8*)(&Bs[row*64 + (((ks*4 + q) ^ (row & 7)) << 3)]);
      }
#pragma unroll
      for (int mi = 0; mi < 2; mi++)
#pragma unroll
        for (int ni = 0; ni < 8; ni++)
          acc[mi][ni] = __builtin_amdgcn_mfma_f32_16x16x32_bf16(af[mi], bfr[ni], acc[mi][ni], 0, 0, 0);
    }
    __syncthreads();
  }
  // epilogue: h = silu(gate)*up * combine_weight (gate=ni 0..3, up=ni 4..7 same lane)
#pragma unroll
  for (int mi = 0; mi < 2; mi++)
#pragma unroll
    for (int r = 0; r < 4; r++) {
      int row = wave*32 + 16*mi + q*4 + r;
      if (row < mrows) {
        int g = g0 + row;
        float wr = sorted_w[g];
        unsigned short* hr = hbuf + (size_t)g * ID + nb;
#pragma unroll
        for (int ni = 0; ni < 4; ni++) {
          float gv = acc[mi][ni][r];
          float uv = acc[mi][ni+4][r];
          float sg = gv / (1.f + __expf(-gv));
          hr[16*ni + m15] = f2bf(sg * uv * wr);
        }
      }
    }
}

// ---- GEMM2: out[tok] += h_e @ wb2_e^T ----
__global__ __launch_bounds__(256) void gemm2_kernel(
    const unsigned short* __restrict__ hbuf, const unsigned short* __restrict__ wb2,
    const int* __restrict__ tiles, const int* __restrict__ numtiles,
    const int* __restrict__ sorted_token, float* __restrict__ out) {
  int mt = blockIdx.y;
  if (mt >= *numtiles) return;
  int e = tiles[mt*3+0], g0 = tiles[mt*3+1], mrows = tiles[mt*3+2];
  int nb = blockIdx.x * BM;   // 128 cols of H

  __shared__ unsigned short As[BM*BK];
  __shared__ unsigned short Bs[BM*BK];

  int tid = threadIdx.x;
  int wave = tid >> 6, lane = tid & 63;
  int m15 = lane & 15, q = lane >> 4;
  const unsigned short* w2e = wb2 + (size_t)e * HD * ID;

  const unsigned short* asrc[4]; const unsigned short* bsrc[4];
  unsigned short* adst[4]; unsigned short* bdst[4];
#pragma unroll
  for (int i = 0; i < 4; i++) {
    int c = i*256 + tid;
    int r = c >> 3, cc = c & 7;
    int sc = ((cc ^ (r & 7)) << 3);
    int rr = r < mrows ? r : 0;
    asrc[i] = hbuf + (size_t)(g0 + rr) * ID + sc;
    bsrc[i] = w2e + (size_t)(nb + r) * ID + sc;
    int dchunk = (i*256 + wave*64) * 8;
    adst[i] = &As[dchunk];
    bdst[i] = &Bs[dchunk];
  }

  floatx4 acc[2][8];
  floatx4 zf = {0.f,0.f,0.f,0.f};
#pragma unroll
  for (int mi=0;mi<2;mi++)
#pragma unroll
    for (int ni=0;ni<8;ni++) acc[mi][ni] = zf;

  for (int k0 = 0; k0 < ID; k0 += BK) {
#pragma unroll
    for (int i = 0; i < 4; i++) GLOAD16(asrc[i] + k0, adst[i]);
#pragma unroll
    for (int i = 0; i < 4; i++) GLOAD16(bsrc[i] + k0, bdst[i]);
    __syncthreads();
#pragma unroll
    for (int ks = 0; ks < 2; ks++) {
      short8 af[2], bfr[8];
#pragma unroll
      for (int mi = 0; mi < 2; mi++) {
        int row = wave*32 + 16*mi + m15;
        af[mi] = *(const short8*)(&As[row*64 + (((ks*4 + q) ^ (row & 7)) << 3)]);
      }
#pragma unroll
      for (int ni = 0; ni < 8; ni++) {
        int row = 16*ni + m15;
        bfr[ni] = *(const short8*)(&Bs[row*64 + (((ks*4 + q) ^ (row & 7)) << 3)]);
      }
#pragma unroll
      for (int mi = 0; mi < 2; mi++)
#pragma unroll
        for (int ni = 0; ni < 8; ni++)
          acc[mi][ni] = __builtin_amdgcn_mfma_f32_16x16x32_bf16(af[mi], bfr[ni], acc[mi][ni], 0, 0, 0);
    }
    __syncthreads();
  }
  // epilogue: atomic combine (h already weight-scaled)
#pragma unroll
  for (int mi = 0; mi < 2; mi++)
#pragma unroll
    for (int r = 0; r < 4; r++) {
      int row = wave*32 + 16*mi + q*4 + r;
      if (row < mrows) {
        int tok = sorted_token[g0 + row];
        float* orow = out + (size_t)tok * HD + nb;
#pragma unroll
        for (int ni = 0; ni < 8; ni++)
          atomicAdd(&orow[16*ni + m15], acc[mi][ni][r]);
      }
    }
}

// ============================================================================
// LEGACY PATH (fp32 weights, reg-staged + convert) — fallback if ws too small
// ============================================================================
__global__ __launch_bounds__(256) void gemm1_legacy(
    const unsigned short* __restrict__ xb, const float* __restrict__ w13,
    const int* __restrict__ tiles, const int* __restrict__ numtiles,
    const int* __restrict__ sorted_token, const float* __restrict__ sorted_w,
    unsigned short* __restrict__ hbuf) {
  int mt = blockIdx.y;
  if (mt >= *numtiles) return;
  int e = tiles[mt*3+0], g0 = tiles[mt*3+1], mrows = tiles[mt*3+2];
  int nb = blockIdx.x * 64;

  __shared__ unsigned short As[BM*LDA];
  __shared__ unsigned short Bs[BM*LDA];

  int tid = threadIdx.x;
  int wave = tid >> 6, lane = tid & 63;
  int m15 = lane & 15, q = lane >> 4;
  const float* w13e = w13 + (size_t)e * (2*ID) * HD;

  const unsigned short* aptr[4]; const float* bptr[4]; int sto[4];
#pragma unroll
  for (int i = 0; i < 4; i++) {
    int c = tid + 256*i;
    int r = c >> 3;
    int col = (c & 7) * 8;
    int rr = r < mrows ? r : 0;
    aptr[i] = xb + (size_t)sorted_token[g0+rr] * HD + col;
    int sr = (r < 64) ? (nb + r) : (ID + nb + r - 64);
    bptr[i] = w13e + (size_t)sr * HD + col;
    sto[i] = r * LDA + col;
  }

  floatx4 acc[2][8];
  floatx4 zf = {0.f,0.f,0.f,0.f};
#pragma unroll
  for (int mi=0;mi<2;mi++)
#pragma unroll
    for (int ni=0;ni<8;ni++) acc[mi][ni] = zf;

  for (int k0 = 0; k0 < HD; k0 += BK) {
    int4 av[4]; float4 b0[4], b1[4];
#pragma unroll
    for (int i = 0; i < 4; i++) {
      av[i] = *(const int4*)(aptr[i] + k0);
      b0[i] = *(const float4*)(bptr[i] + k0);
      b1[i] = *(const float4*)(bptr[i] + k0 + 4);
    }
#pragma unroll
    for (int i = 0; i < 4; i++) {
      *(int4*)(&As[sto[i]]) = av[i];
      union { unsigned short s[8]; int4 v; } p;
      p.s[0]=f2bf(b0[i].x); p.s[1]=f2bf(b0[i].y); p.s[2]=f2bf(b0[i].z); p.s[3]=f2bf(b0[i].w);
      p.s[4]=f2bf(b1[i].x); p.s[5]=f2bf(b1[i].y); p.s[6]=f2bf(b1[i].z); p.s[7]=f2bf(b1[i].w);
      *(int4*)(&Bs[sto[i]]) = p.v;
    }
    __syncthreads();
#pragma unroll
    for (int ks = 0; ks < 2; ks++) {
      int ko = ks*32 + q*8;
      short8 af[2], bfr[8];
#pragma unroll
      for (int mi = 0; mi < 2; mi++)
        af[mi] = *(const short8*)(&As[(wave*32 + 16*mi + m15)*LDA + ko]);
#pragma unroll
      for (int ni = 0; ni < 8; ni++)
        bfr[ni] = *(const short8*)(&Bs[(16*ni + m15)*LDA + ko]);
#pragma unroll
      for (int mi = 0; mi < 2; mi++)
#pragma unroll
        for (int ni = 0; ni < 8; ni++)
          acc[mi][ni] = __builtin_amdgcn_mfma_f32_16x16x32_bf16(af[mi], bfr[ni], acc[mi][ni], 0, 0, 0);
    }
    __syncthreads();
  }
#pragma unroll
  for (int mi = 0; mi < 2; mi++)
#pragma unroll
    for (int r = 0; r < 4; r++) {
      int row = wave*32 + 16*mi + q*4 + r;
      if (row < mrows) {
        int g = g0 + row;
        float wr = sorted_w[g];
        unsigned short* hr = hbuf + (size_t)g * ID + nb;
#pragma unroll
        for (int ni = 0; ni < 4; ni++) {
          float gv = acc[mi][ni][r];
          float uv = acc[mi][ni+4][r];
          float sg = gv / (1.f + __expf(-gv));
          hr[16*ni + m15] = f2bf(sg * uv * wr);
        }
      }
    }
}

__global__ __launch_bounds__(256) void gemm2_legacy(
    const unsigned short* __restrict__ hbuf, const float* __restrict__ w2,
    const int* __restrict__ tiles, const int* __restrict__ numtiles,
    const int* __restrict__ sorted_token, float* __restrict__ out) {
  int mt = blockIdx.y;
  if (mt >= *numtiles) return;
  int e = tiles[mt*3+0], g0 = tiles[mt*3+1], mrows = tiles[mt*3+2];
  int nb = blockIdx.x * BM;

  __shared__ unsigned short As[BM*LDA];
  __shared__ unsigned short Bs[BM*LDA];

  int tid = threadIdx.x;
  int wave = tid >> 6, lane = tid & 63;
  int m15 = lane & 15, q = lane >> 4;
  const float* w2e = w2 + (size_t)e * HD * ID;

  const unsigned short* aptr[4]; const float* bptr[4]; int sto[4];
#pragma unroll
  for (int i = 0; i < 4; i++) {
    int c = tid + 256*i;
    int r = c >> 3;
    int col = (c & 7) * 8;
    int rr = r < mrows ? r : 0;
    aptr[i] = hbuf + (size_t)(g0 + rr) * ID + col;
    bptr[i] = w2e + (size_t)(nb + r) * ID + col;
    sto[i] = r * LDA + col;
  }

  floatx4 acc[2][8];
  floatx4 zf = {0.f,0.f,0.f,0.f};
#pragma unroll
  for (int mi=0;mi<2;mi++)
#pragma unroll
    for (int ni=0;ni<8;ni++) acc[mi][ni] = zf;

  for (int k0 = 0; k0 < ID; k0 += BK) {
    int4 av[4]; float4 b0[4], b1[4];
#pragma unroll
    for (int i = 0; i < 4; i++) {
      av[i] = *(const int4*)(aptr[i] + k0);
      b0[i] = *(const float4*)(bptr[i] + k0);
      b1[i] = *(const float4*)(bptr[i] + k0 + 4);
    }
#pragma unroll
    for (int i = 0; i < 4; i++) {
      *(int4*)(&As[sto[i]]) = av[i];
      union { unsigned short s[8]; int4 v; } p;
      p.s[0]=f2bf(b0[i].x); p.s[1]=f2bf(b0[i].y); p.s[2]=f2bf(b0[i].z); p.s[3]=f2bf(b0[i].w);
      p.s[4]=f2bf(b1[i].x); p.s[5]=f2bf(b1[i].y); p.s[6]=f2bf(b1[i].z); p.s[7]=f2bf(b1[i].w);
      *(int4*)(&Bs[sto[i]]) = p.v;
    }
    __syncthreads();
#pragma unroll
    for (int ks = 0; ks < 2; ks++) {
      int ko = ks*32 + q*8;
      short8 af[2], bfr[8];
#pragma unroll
      for (int mi = 0; mi < 2; mi++)
        af[mi] = *(const short8*)(&As[(wave*32 + 16*mi + m15)*LDA + ko]);
#pragma unroll
      for (int ni = 0; ni < 8; ni++)
        bfr[ni] = *(const short8*)(&Bs[(16*ni + m15)*LDA + ko]);
#pragma unroll
      for (int mi = 0; mi < 2; mi++)
#pragma unroll
        for (int ni = 0; ni < 8; ni++)
          acc[mi][ni] = __builtin_amdgcn_mfma_f32_16x16x32_bf16(af[mi], bfr[ni], acc[mi][ni], 0, 0, 0);
    }
    __syncthreads();
  }
#pragma unroll
  for (int mi = 0; mi < 2; mi++)
#pragma unroll
    for (int r = 0; r < 4; r++) {
      int row = wave*32 + 16*mi + q*4 + r;
      if (row < mrows) {
        int tok = sorted_token[g0 + row];
        float* orow = out + (size_t)tok * HD + nb;
#pragma unroll
        for (int ni = 0; ni < 8; ni++)
          atomicAdd(&orow[16*ni + m15], acc[mi][ni][r]);
      }
    }
}

// ---------------- workspace layout (bytes) ----------------
#define WS_COUNTS   0u
#define WS_CURSOR   128u
#define WS_OFFSETS  256u
#define WS_NUMTILES 512u
#define WS_TILES    1024u
#define WS_TOPKI    4096u
#define WS_TOPKW    (WS_TOPKI + TKR*4u)     // 69632
#define WS_SORTTOK  (WS_TOPKW + TKR*4u)     // 135168
#define WS_SORTW    (WS_SORTTOK + TKR*4u)   // 200704
#define WS_XB       (WS_SORTW + TKR*4u)     // 266240
#define WS_HBUF     (WS_XB + (size_t)NT*HD*2u)
#define WS_WB13     (WS_HBUF + (size_t)TKR*ID*2u)            // ~50.6 MB
#define WS_WB2      (WS_WB13 + (size_t)NE*2*ID*HD*2u)        // +268.4 MB
#define WS_END      (WS_WB2 + (size_t)NE*HD*ID*2u)           // +134.2 MB -> ~453.3 MB

extern "C" void kernel_launch(void* const* d_in, const int* in_sizes, int n_in,
                              void* d_out, int out_size, void* d_ws, size_t ws_size,
                              hipStream_t stream) {
  const float* x      = (const float*)d_in[0];
  const float* gate_w = (const float*)d_in[1];
  const float* bias   = (const float*)d_in[2];
  const float* w13    = (const float*)d_in[3];
  const float* w2     = (const float*)d_in[4];
  float* out = (float*)d_out;

  char* ws = (char*)d_ws;
  int*   counts   = (int*)(ws + WS_COUNTS);
  int*   cursor   = (int*)(ws + WS_CURSOR);
  int*   offsets  = (int*)(ws + WS_OFFSETS);
  int*   numtiles = (int*)(ws + WS_NUMTILES);
  int*   tiles    = (int*)(ws + WS_TILES);
  int*   topk_idx = (int*)(ws + WS_TOPKI);
  float* topk_w   = (float*)(ws + WS_TOPKW);
  int*   sorted_token = (int*)(ws + WS_SORTTOK);
  float* sorted_w     = (float*)(ws + WS_SORTW);
  unsigned short* xb   = (unsigned short*)(ws + WS_XB);
  unsigned short* hbuf = (unsigned short*)(ws + WS_HBUF);
  unsigned short* wb13 = (unsigned short*)(ws + WS_WB13);
  unsigned short* wb2  = (unsigned short*)(ws + WS_WB2);

  hipMemsetAsync(ws, 0, 1024, stream);                         // counts/cursor
  hipMemsetAsync(d_out, 0, (size_t)out_size * 4, stream);      // combine target

  cvt_kernel<<<4096, 256, 0, stream>>>(x, xb, (size_t)NT*HD);
  router_kernel<<<NT, 256, 0, stream>>>(x, gate_w, bias, topk_idx, topk_w, counts);
  plan_kernel<<<1, 64, 0, stream>>>(counts, offsets, cursor, tiles, numtiles);
  scatter_kernel<<<TKR/256, 256, 0, stream>>>(topk_idx, topk_w, offsets, cursor,
                                              sorted_token, sorted_w);

  if (ws_size >= WS_END) {
    // bf16-weight fast path
    cvt_kernel<<<8192, 256, 0, stream>>>(w13, wb13, (size_t)NE*2*ID*HD);
    cvt_kernel<<<8192, 256, 0, stream>>>(w2,  wb2,  (size_t)NE*HD*ID);
    gemm1_kernel<<<dim3(2*ID/BM, MAXTILES), 256, 0, stream>>>(xb, wb13, tiles, numtiles,
                                                              sorted_token, sorted_w, hbuf);
    gemm2_kernel<<<dim3(HD/BM, MAXTILES), 256, 0, stream>>>(hbuf, wb2, tiles, numtiles,
                                                            sorted_token, out);
  } else {
    // fallback: previous verified path
    gemm1_legacy<<<dim3(2*ID/BM, MAXTILES), 256, 0, stream>>>(xb, w13, tiles, numtiles,
                                                              sorted_token, sorted_w, hbuf);
    gemm2_legacy<<<dim3(HD/BM, MAXTILES), 256, 0, stream>>>(hbuf, w2, tiles, numtiles,
                                                            sorted_token, out);
  }
}

// Round 2
// 1587.070 us; speedup vs baseline: 1.0425x; 1.0425x over previous
//
#include <hip/hip_runtime.h>
#include <hip/hip_bf16.h>

#define NE 32      // experts
#define NK 4       // top-k
#define HD 2048    // hidden
#define ID 1024    // intermediate
#define NT 4096    // tokens
#define TKR (NT*NK) // total routed rows = 16384
#define BM 128
#define BK 64
#define MAXTILES 160

typedef __attribute__((ext_vector_type(8))) short short8;
typedef __attribute__((ext_vector_type(4))) float floatx4;

__device__ __forceinline__ unsigned short f2bf(float f) {
  // round-to-nearest-even fp32 -> bf16 (integer path)
  unsigned u = __builtin_bit_cast(unsigned, f);
  unsigned r = u + 0x7fffu + ((u >> 16) & 1u);
  return (unsigned short)(r >> 16);
}

__device__ __forceinline__ unsigned pk2bf(float lo, float hi) {
  // pack 2 fp32 -> 2 bf16 RNE; compiler emits v_cvt_pk_bf16_f32
  unsigned short a = __builtin_bit_cast(unsigned short, __float2bfloat16(lo));
  unsigned short b = __builtin_bit_cast(unsigned short, __float2bfloat16(hi));
  return (unsigned)a | ((unsigned)b << 16);
}

// async global->LDS, 16B per lane; LDS dest = wave-uniform base + lane*16
#define GLOAD16(g, l) __builtin_amdgcn_global_load_lds( \
    (const __attribute__((address_space(1))) void*)(g), \
    (__attribute__((address_space(3))) void*)(l), 16, 0, 0)

// ---------------- x fp32 -> bf16 (grid-stride) ----------------
__global__ __launch_bounds__(256) void cvt_kernel(const float* __restrict__ src,
                                                  unsigned short* __restrict__ dst,
                                                  size_t n) {
  size_t stride = (size_t)gridDim.x * 256 * 8;
  for (size_t i = ((size_t)blockIdx.x * 256 + threadIdx.x) * 8; i < n; i += stride) {
    float4 a = *(const float4*)(src + i);
    float4 b = *(const float4*)(src + i + 4);
    union { unsigned short s[8]; int4 v; } p;
    p.s[0]=f2bf(a.x); p.s[1]=f2bf(a.y); p.s[2]=f2bf(a.z); p.s[3]=f2bf(a.w);
    p.s[4]=f2bf(b.x); p.s[5]=f2bf(b.y); p.s[6]=f2bf(b.z); p.s[7]=f2bf(b.w);
    *(int4*)(dst + i) = p.v;
  }
}

// ---------------- router: logits -> sigmoid -> top4 -> weights ----------------
__global__ __launch_bounds__(256) void router_kernel(
    const float* __restrict__ x, const float* __restrict__ gate_w,
    const float* __restrict__ bias, int* __restrict__ topk_idx,
    float* __restrict__ topk_w, int* __restrict__ counts) {
  int t = blockIdx.x;
  int tid = threadIdx.x;
  int e = tid >> 3, l8 = tid & 7;     // 8 threads per expert
  const float* xr = x + (size_t)t * HD;
  const float* gr = gate_w + (size_t)e * HD;
  float s = 0.f;
  int base = l8 * 256;
#pragma unroll 8
  for (int i = 0; i < 256; i += 4) {
    float4 xv = *(const float4*)(xr + base + i);
    float4 gv = *(const float4*)(gr + base + i);
    s += xv.x*gv.x + xv.y*gv.y + xv.z*gv.z + xv.w*gv.w;
  }
  s += __shfl_down(s, 4, 64);
  s += __shfl_down(s, 2, 64);
  s += __shfl_down(s, 1, 64);
  __shared__ float sc[NE];
  if (l8 == 0) sc[e] = s;
  __syncthreads();
  if (tid == 0) {
    float sig[NE], sel[NE];
    for (int i = 0; i < NE; i++) {
      sig[i] = 1.f / (1.f + expf(-sc[i]));
      sel[i] = sig[i] + bias[i];       // bias affects selection only
    }
    int idxs[NK]; float wsum = 0.f;
    for (int k = 0; k < NK; k++) {
      int bi = 0; float bv = -1e30f;
      for (int i = 0; i < NE; i++)
        if (sel[i] > bv) { bv = sel[i]; bi = i; }   // ties -> lowest index
      sel[bi] = -1e30f;
      idxs[k] = bi; wsum += sig[bi];
    }
    for (int k = 0; k < NK; k++) {
      topk_idx[t*NK + k] = idxs[k];
      topk_w[t*NK + k] = sig[idxs[k]] / wsum;
      atomicAdd(&counts[idxs[k]], 1);
    }
  }
}

// ---------------- plan: offsets + tile descriptors ----------------
__global__ void plan_kernel(const int* __restrict__ counts, int* __restrict__ offsets,
                            int* __restrict__ cursor, int* __restrict__ tiles,
                            int* __restrict__ numtiles) {
  if (threadIdx.x == 0) {
    int off = 0;
    for (int e = 0; e < NE; e++) { offsets[e] = off; off += counts[e]; cursor[e] = 0; }
    offsets[NE] = off;
    int nt = 0;
    for (int e = 0; e < NE; e++) {
      int start = offsets[e], n = counts[e];
      for (int r = 0; r < n; r += BM) {
        tiles[nt*3+0] = e; tiles[nt*3+1] = start + r; tiles[nt*3+2] = min(BM, n - r);
        nt++;
      }
    }
    *numtiles = nt;
  }
}

// ---------------- scatter to expert-sorted order ----------------
__global__ __launch_bounds__(256) void scatter_kernel(
    const int* __restrict__ topk_idx, const float* __restrict__ topk_w,
    const int* __restrict__ offsets, int* __restrict__ cursor,
    int* __restrict__ sorted_token, float* __restrict__ sorted_w) {
  int i = blockIdx.x * 256 + threadIdx.x;   // [0, TKR)
  int e = topk_idx[i];
  int pos = offsets[e] + atomicAdd(&cursor[e], 1);
  sorted_token[pos] = i >> 2;
  sorted_w[pos] = topk_w[i];
}

// ============================================================================
// GEMMs: 2-phase double-buffered pipeline.
//  A (bf16): global_load_lds with pre-swizzled source (rule 21, verified R1).
//  B (fp32 weights): reg-stage (T14 split) -> cvt_pk bf16 -> swizzled ds_write.
//  Four DISTINCT __shared__ arrays so alias analysis keeps the prefetch's
//  vmcnt un-drained until __syncthreads (one barrier per K-step).
//  Swizzle: LDS chunk (r, kc^(r&7)) holds logical chunk kc; reads XOR the same.
// ============================================================================

// ---- GEMM1: gu = X_e @ w13_e^T, fused SwiGLU*weight -> h bf16 ----
__global__ __launch_bounds__(256, 2) void gemm1_kernel(
    const unsigned short* __restrict__ xb, const float* __restrict__ w13,
    const int* __restrict__ tiles, const int* __restrict__ numtiles,
    const int* __restrict__ sorted_token, const float* __restrict__ sorted_w,
    unsigned short* __restrict__ hbuf) {
  // bijective XCD chunk swizzle over flat grid (2560 % 8 == 0)
  int wg = blockIdx.x;
  int wgs = (wg & 7) * ((16 * MAXTILES) >> 3) + (wg >> 3);
  int mt = wgs >> 4;
  int xcol = wgs & 15;
  if (mt >= *numtiles) return;
  int e = tiles[mt*3+0], g0 = tiles[mt*3+1], mrows = tiles[mt*3+2];
  int nb = xcol * 64;   // gate-col base; up cols at +ID

  __shared__ unsigned short As0[BM*BK];
  __shared__ unsigned short Bs0[BM*BK];
  __shared__ unsigned short As1[BM*BK];
  __shared__ unsigned short Bs1[BM*BK];

  int tid = threadIdx.x;
  int wave = tid >> 6, lane = tid & 63;
  int m15 = lane & 15, q = lane >> 4;
  const float* w13e = w13 + (size_t)e * (2*ID) * HD;

  // staging descriptors: call i covers chunk c = i*256 + tid
  const unsigned short* asrc[4]; const float* bsrc[4];
  int dch[4], bsto[4];
#pragma unroll
  for (int i = 0; i < 4; i++) {
    int c = i*256 + tid;
    int r = c >> 3, cc = c & 7;
    int sc = ((cc ^ (r & 7)) << 3);              // A: swizzled SOURCE col
    int rr = r < mrows ? r : 0;                  // tail clamp
    asrc[i] = xb + (size_t)sorted_token[g0+rr] * HD + sc;
    int sr = (r < 64) ? (nb + r) : (ID + nb + r - 64);  // gate rows | up rows
    bsrc[i] = w13e + (size_t)sr * HD + cc*8;     // B: linear fp32 source
    dch[i]  = (i*256 + wave*64) * 8;             // A: wave-uniform LDS dest
    bsto[i] = r*64 + ((cc ^ (r & 7)) << 3);      // B: swizzled LDS write
  }

  floatx4 acc[2][8];
  floatx4 zf = {0.f,0.f,0.f,0.f};
#pragma unroll
  for (int mi=0;mi<2;mi++)
#pragma unroll
    for (int ni=0;ni<8;ni++) acc[mi][ni] = zf;

  float4 pb0[4], pb1[4];
  auto stageA = [&](unsigned short* dst, int k) {
#pragma unroll
    for (int i = 0; i < 4; i++) GLOAD16(asrc[i] + k, dst + dch[i]);
  };
  auto loadB = [&](int k) {
#pragma unroll
    for (int i = 0; i < 4; i++) {
      pb0[i] = *(const float4*)(bsrc[i] + k);
      pb1[i] = *(const float4*)(bsrc[i] + k + 4);
    }
  };
  auto writeB = [&](unsigned short* Bsb) {
#pragma unroll
    for (int i = 0; i < 4; i++) {
      union { unsigned u[4]; int4 v; } p;
      p.u[0] = pk2bf(pb0[i].x, pb0[i].y);
      p.u[1] = pk2bf(pb0[i].z, pb0[i].w);
      p.u[2] = pk2bf(pb1[i].x, pb1[i].y);
      p.u[3] = pk2bf(pb1[i].z, pb1[i].w);
      *(int4*)(Bsb + bsto[i]) = p.v;
    }
  };
  auto compute = [&](const unsigned short* Asb, const unsigned short* Bsb) {
#pragma unroll
    for (int ks = 0; ks < 2; ks++) {
      short8 af[2], bfr[8];
#pragma unroll
      for (int mi = 0; mi < 2; mi++) {
        int row = wave*32 + 16*mi + m15;
        af[mi] = *(const short8*)(Asb + row*64 + (((ks*4 + q) ^ (row & 7)) << 3));
      }
#pragma unroll
      for (int ni = 0; ni < 8; ni++) {
        int row = 16*ni + m15;
        bfr[ni] = *(const short8*)(Bsb + row*64 + (((ks*4 + q) ^ (row & 7)) << 3));
      }
#pragma unroll
      for (int mi = 0; mi < 2; mi++)
#pragma unroll
        for (int ni = 0; ni < 8; ni++)
          acc[mi][ni] = __builtin_amdgcn_mfma_f32_16x16x32_bf16(af[mi], bfr[ni], acc[mi][ni], 0, 0, 0);
    }
  };

  // prologue: tile k=0 into buffer 0
  stageA(As0, 0);
  loadB(0); writeB(Bs0);
  __syncthreads();
  constexpr int NS2 = HD / (2*BK);   // 16 double-steps
  for (int t = 0; t < NS2; ++t) {
    int kA = t * 2 * BK;
    // phase A: prefetch kA+BK -> buf1; compute buf0
    stageA(As1, kA + BK); loadB(kA + BK);
    compute(As0, Bs0);
    writeB(Bs1);
    __syncthreads();
    // phase B: prefetch kA+2BK -> buf0; compute buf1
    bool more = (t + 1 < NS2);
    if (more) { stageA(As0, kA + 2*BK); loadB(kA + 2*BK); }
    compute(As1, Bs1);
    if (more) writeB(Bs0);
    __syncthreads();
  }

  // epilogue: h = silu(gate)*up * combine_weight (gate=ni 0..3, up=ni 4..7)
#pragma unroll
  for (int mi = 0; mi < 2; mi++)
#pragma unroll
    for (int r = 0; r < 4; r++) {
      int row = wave*32 + 16*mi + q*4 + r;
      if (row < mrows) {
        int g = g0 + row;
        float wr = sorted_w[g];
        unsigned short* hr = hbuf + (size_t)g * ID + nb;
#pragma unroll
        for (int ni = 0; ni < 4; ni++) {
          float gv = acc[mi][ni][r];
          float uv = acc[mi][ni+4][r];
          float sg = gv / (1.f + __expf(-gv));
          hr[16*ni + m15] = f2bf(sg * uv * wr);
        }
      }
    }
}

// ---- GEMM2: out[tok] += h_e @ w2_e^T ----
__global__ __launch_bounds__(256, 2) void gemm2_kernel(
    const unsigned short* __restrict__ hbuf, const float* __restrict__ w2,
    const int* __restrict__ tiles, const int* __restrict__ numtiles,
    const int* __restrict__ sorted_token, float* __restrict__ out) {
  int wg = blockIdx.x;
  int wgs = (wg & 7) * ((16 * MAXTILES) >> 3) + (wg >> 3);
  int mt = wgs >> 4;
  int xcol = wgs & 15;
  if (mt >= *numtiles) return;
  int e = tiles[mt*3+0], g0 = tiles[mt*3+1], mrows = tiles[mt*3+2];
  int nb = xcol * BM;   // 128 cols of H

  __shared__ unsigned short As0[BM*BK];
  __shared__ unsigned short Bs0[BM*BK];
  __shared__ unsigned short As1[BM*BK];
  __shared__ unsigned short Bs1[BM*BK];

  int tid = threadIdx.x;
  int wave = tid >> 6, lane = tid & 63;
  int m15 = lane & 15, q = lane >> 4;
  const float* w2e = w2 + (size_t)e * HD * ID;

  const unsigned short* asrc[4]; const float* bsrc[4];
  int dch[4], bsto[4];
#pragma unroll
  for (int i = 0; i < 4; i++) {
    int c = i*256 + tid;
    int r = c >> 3, cc = c & 7;
    int sc = ((cc ^ (r & 7)) << 3);
    int rr = r < mrows ? r : 0;
    asrc[i] = hbuf + (size_t)(g0 + rr) * ID + sc;
    bsrc[i] = w2e + (size_t)(nb + r) * ID + cc*8;
    dch[i]  = (i*256 + wave*64) * 8;
    bsto[i] = r*64 + ((cc ^ (r & 7)) << 3);
  }

  floatx4 acc[2][8];
  floatx4 zf = {0.f,0.f,0.f,0.f};
#pragma unroll
  for (int mi=0;mi<2;mi++)
#pragma unroll
    for (int ni=0;ni<8;ni++) acc[mi][ni] = zf;

  float4 pb0[4], pb1[4];
  auto stageA = [&](unsigned short* dst, int k) {
#pragma unroll
    for (int i = 0; i < 4; i++) GLOAD16(asrc[i] + k, dst + dch[i]);
  };
  auto loadB = [&](int k) {
#pragma unroll
    for (int i = 0; i < 4; i++) {
      pb0[i] = *(const float4*)(bsrc[i] + k);
      pb1[i] = *(const float4*)(bsrc[i] + k + 4);
    }
  };
  auto writeB = [&](unsigned short* Bsb) {
#pragma unroll
    for (int i = 0; i < 4; i++) {
      union { unsigned u[4]; int4 v; } p;
      p.u[0] = pk2bf(pb0[i].x, pb0[i].y);
      p.u[1] = pk2bf(pb0[i].z, pb0[i].w);
      p.u[2] = pk2bf(pb1[i].x, pb1[i].y);
      p.u[3] = pk2bf(pb1[i].z, pb1[i].w);
      *(int4*)(Bsb + bsto[i]) = p.v;
    }
  };
  auto compute = [&](const unsigned short* Asb, const unsigned short* Bsb) {
#pragma unroll
    for (int ks = 0; ks < 2; ks++) {
      short8 af[2], bfr[8];
#pragma unroll
      for (int mi = 0; mi < 2; mi++) {
        int row = wave*32 + 16*mi + m15;
        af[mi] = *(const short8*)(Asb + row*64 + (((ks*4 + q) ^ (row & 7)) << 3));
      }
#pragma unroll
      for (int ni = 0; ni < 8; ni++) {
        int row = 16*ni + m15;
        bfr[ni] = *(const short8*)(Bsb + row*64 + (((ks*4 + q) ^ (row & 7)) << 3));
      }
#pragma unroll
      for (int mi = 0; mi < 2; mi++)
#pragma unroll
        for (int ni = 0; ni < 8; ni++)
          acc[mi][ni] = __builtin_amdgcn_mfma_f32_16x16x32_bf16(af[mi], bfr[ni], acc[mi][ni], 0, 0, 0);
    }
  };

  stageA(As0, 0);
  loadB(0); writeB(Bs0);
  __syncthreads();
  constexpr int NS2 = ID / (2*BK);   // 8 double-steps
  for (int t = 0; t < NS2; ++t) {
    int kA = t * 2 * BK;
    stageA(As1, kA + BK); loadB(kA + BK);
    compute(As0, Bs0);
    writeB(Bs1);
    __syncthreads();
    bool more = (t + 1 < NS2);
    if (more) { stageA(As0, kA + 2*BK); loadB(kA + 2*BK); }
    compute(As1, Bs1);
    if (more) writeB(Bs0);
    __syncthreads();
  }

  // epilogue: atomic combine (h already weight-scaled)
#pragma unroll
  for (int mi = 0; mi < 2; mi++)
#pragma unroll
    for (int r = 0; r < 4; r++) {
      int row = wave*32 + 16*mi + q*4 + r;
      if (row < mrows) {
        int tok = sorted_token[g0 + row];
        float* orow = out + (size_t)tok * HD + nb;
#pragma unroll
        for (int ni = 0; ni < 8; ni++)
          atomicAdd(&orow[16*ni + m15], acc[mi][ni][r]);
      }
    }
}

// ---------------- workspace layout (bytes) ----------------
#define WS_COUNTS   0u
#define WS_CURSOR   128u
#define WS_OFFSETS  256u
#define WS_NUMTILES 512u
#define WS_TILES    1024u
#define WS_TOPKI    4096u
#define WS_TOPKW    (WS_TOPKI + TKR*4u)     // 69632
#define WS_SORTTOK  (WS_TOPKW + TKR*4u)     // 135168
#define WS_SORTW    (WS_SORTTOK + TKR*4u)   // 200704
#define WS_XB       (WS_SORTW + TKR*4u)     // 266240
#define WS_HBUF     (WS_XB + (size_t)NT*HD*2u)
// total = WS_HBUF + TKR*ID*2 = ~50.6 MB

extern "C" void kernel_launch(void* const* d_in, const int* in_sizes, int n_in,
                              void* d_out, int out_size, void* d_ws, size_t ws_size,
                              hipStream_t stream) {
  const float* x      = (const float*)d_in[0];
  const float* gate_w = (const float*)d_in[1];
  const float* bias   = (const float*)d_in[2];
  const float* w13    = (const float*)d_in[3];
  const float* w2     = (const float*)d_in[4];
  float* out = (float*)d_out;

  char* ws = (char*)d_ws;
  int*   counts   = (int*)(ws + WS_COUNTS);
  int*   cursor   = (int*)(ws + WS_CURSOR);
  int*   offsets  = (int*)(ws + WS_OFFSETS);
  int*   numtiles = (int*)(ws + WS_NUMTILES);
  int*   tiles    = (int*)(ws + WS_TILES);
  int*   topk_idx = (int*)(ws + WS_TOPKI);
  float* topk_w   = (float*)(ws + WS_TOPKW);
  int*   sorted_token = (int*)(ws + WS_SORTTOK);
  float* sorted_w     = (float*)(ws + WS_SORTW);
  unsigned short* xb   = (unsigned short*)(ws + WS_XB);
  unsigned short* hbuf = (unsigned short*)(ws + WS_HBUF);

  hipMemsetAsync(ws, 0, 1024, stream);                         // counts/cursor
  hipMemsetAsync(d_out, 0, (size_t)out_size * 4, stream);      // combine target

  cvt_kernel<<<4096, 256, 0, stream>>>(x, xb, (size_t)NT*HD);
  router_kernel<<<NT, 256, 0, stream>>>(x, gate_w, bias, topk_idx, topk_w, counts);
  plan_kernel<<<1, 64, 0, stream>>>(counts, offsets, cursor, tiles, numtiles);
  scatter_kernel<<<TKR/256, 256, 0, stream>>>(topk_idx, topk_w, offsets, cursor,
                                              sorted_token, sorted_w);
  gemm1_kernel<<<16*MAXTILES, 256, 0, stream>>>(xb, w13, tiles, numtiles,
                                                sorted_token, sorted_w, hbuf);
  gemm2_kernel<<<16*MAXTILES, 256, 0, stream>>>(hbuf, w2, tiles, numtiles,
                                                sorted_token, out);
}